// Round 3
// baseline (318.425 us; speedup 1.0000x reference)
//
#include <hip/hip_runtime.h>
#include <hip/hip_bf16.h>
#include <math.h>

// Problem constants: B=32, O=4096, F=256, H=8, HID=128
#define MB_ 131072
#define F_  256
#define HID_ 128
#define H_  8
#define O_  4096
#define B_  32

typedef __attribute__((ext_vector_type(8))) short short8;
typedef __attribute__((ext_vector_type(4))) float f32x4;

static __device__ __forceinline__ unsigned short f2bf(float f) {
    unsigned int u = __float_as_uint(f);
    unsigned int r = (u + 0x7fffu + ((u >> 16) & 1u)) >> 16;  // RNE
    return (unsigned short)r;
}
static __device__ __forceinline__ float bf2f(unsigned short u) {
    return __uint_as_float(((unsigned int)u) << 16);
}

// ---------------- Prep: transpose + bf16-cast weights -----------------------
__global__ __launch_bounds__(256) void k_prep(
    const float* __restrict__ W_in, const float* __restrict__ W_blk,
    unsigned short* __restrict__ WinT, unsigned short* __restrict__ WblkT)
{
    const int idx = blockIdx.x * 256 + threadIdx.x;
    if (idx < 32768) {
        const int n = idx >> 8, k = idx & 255;
        WinT[idx] = f2bf(W_in[(size_t)k * HID_ + n]);
    } else {
        const int i2 = idx - 32768;  // < 16384
        const int n = i2 >> 7, k = i2 & 127;
        WblkT[i2] = f2bf(W_blk[(size_t)k * HID_ + n]);
    }
}

// ---------------- Phase A: h = relu(x@W_in+b_in); z=h@W_blk BN partials -----
// grid 1024, block 256 (4 waves). Tile 128 rows. GEMM1 K=256, GEMM2 K=128.
// h tile kept in LDS (hb_s) between the two GEMMs; z is never materialized.
__global__ __launch_bounds__(256) void k_phaseA(
    const float* __restrict__ x, const unsigned short* __restrict__ WinT,
    const unsigned short* __restrict__ WblkT,
    const float* __restrict__ b_in, const float* __restrict__ b_blk,
    unsigned short* __restrict__ h_out, float* __restrict__ mask_out,
    float* __restrict__ sumP, float* __restrict__ sumsqP)
{
    __shared__ unsigned short a_s[128 * 40];     // x staging (bf16), pad 40
    __shared__ unsigned short b_s[128 * 40];     // weight staging
    __shared__ unsigned short hb_s[128 * 136];   // h tile, LDH=136 (16B rows)
    __shared__ float msum_s[128];
    __shared__ float csum_s[128], csumsq_s[128];

    const int tid = threadIdx.x;
    const int R0 = blockIdx.x * 128;
    const int lp_r = tid >> 3;   // 0..31
    const int lp_c = tid & 7;    // 0..7
    const int wave = tid >> 6;
    const int wrow = wave >> 1, wcol = wave & 1;
    const int lane = tid & 63;
    const int lm = lane & 15, quad = lane >> 4;

    if (tid < 128) { msum_s[tid] = 0.f; csum_s[tid] = 0.f; csumsq_s[tid] = 0.f; }
    float ms[4] = {0.f, 0.f, 0.f, 0.f};

    f32x4 acc[4][4];
#pragma unroll
    for (int i = 0; i < 4; i++)
#pragma unroll
        for (int j = 0; j < 4; j++) acc[i][j] = (f32x4){0.f, 0.f, 0.f, 0.f};

    // ---- GEMM1: K = 256 in 8 tiles of 32 ----
    for (int kt = 0; kt < 8; kt++) {
#pragma unroll
        for (int p = 0; p < 4; p++) {
            const int r = lp_r + 32 * p;
            const float4 v = *(const float4*)(x + (size_t)(R0 + r) * F_ + kt * 32 + lp_c * 4);
            ms[p] += v.x * v.x + v.y * v.y + v.z * v.z + v.w * v.w;
            ushort4 o;
            o.x = f2bf(v.x); o.y = f2bf(v.y); o.z = f2bf(v.z); o.w = f2bf(v.w);
            *(ushort4*)(&a_s[r * 40 + lp_c * 4]) = o;
        }
#pragma unroll
        for (int p = 0; p < 4; p++) {
            const int n = lp_r + 32 * p;
            const ushort4 wv = *(const ushort4*)(WinT + (size_t)n * F_ + kt * 32 + lp_c * 4);
            *(ushort4*)(&b_s[n * 40 + lp_c * 4]) = wv;
        }
        __syncthreads();
        short8 af[4], bfr[4];
#pragma unroll
        for (int mi = 0; mi < 4; mi++)
            af[mi] = *(const short8*)(&a_s[(wrow * 64 + mi * 16 + lm) * 40 + quad * 8]);
#pragma unroll
        for (int ni = 0; ni < 4; ni++)
            bfr[ni] = *(const short8*)(&b_s[(wcol * 64 + ni * 16 + lm) * 40 + quad * 8]);
#pragma unroll
        for (int mi = 0; mi < 4; mi++)
#pragma unroll
            for (int ni = 0; ni < 4; ni++)
                acc[mi][ni] = __builtin_amdgcn_mfma_f32_16x16x32_bf16(af[mi], bfr[ni], acc[mi][ni], 0, 0, 0);
        __syncthreads();
    }

    // ---- epilogue 1: bias+relu -> hb_s; mask partials ----
#pragma unroll
    for (int p = 0; p < 4; p++) atomicAdd(&msum_s[lp_r + 32 * p], ms[p]);
    {
        float bcol[4];
#pragma unroll
        for (int ni = 0; ni < 4; ni++) bcol[ni] = b_in[wcol * 64 + ni * 16 + lm];
#pragma unroll
        for (int mi = 0; mi < 4; mi++)
#pragma unroll
            for (int r = 0; r < 4; r++) {
                const int row = wrow * 64 + mi * 16 + quad * 4 + r;
#pragma unroll
                for (int ni = 0; ni < 4; ni++) {
                    const int col = wcol * 64 + ni * 16 + lm;
                    hb_s[row * 136 + col] = f2bf(fmaxf(acc[mi][ni][r] + bcol[ni], 0.f));
                }
            }
    }
    __syncthreads();

    // ---- coalesced h store from LDS; mask store ----
    {
        const int row = tid >> 1, half = tid & 1;
#pragma unroll
        for (int c8 = 0; c8 < 8; c8++) {
            const short8 v = *(const short8*)(&hb_s[row * 136 + half * 64 + c8 * 8]);
            *(short8*)(h_out + (size_t)(R0 + row) * HID_ + half * 64 + c8 * 8) = v;
        }
    }
    if (tid < 128) mask_out[R0 + tid] = (msum_s[tid] != 0.f) ? 1.f : 0.f;

    // ---- GEMM2: z = h @ W_blk, K = 128 in 4 tiles of 32 (A from hb_s) ----
#pragma unroll
    for (int i = 0; i < 4; i++)
#pragma unroll
        for (int j = 0; j < 4; j++) acc[i][j] = (f32x4){0.f, 0.f, 0.f, 0.f};
    for (int kt = 0; kt < 4; kt++) {
#pragma unroll
        for (int p = 0; p < 4; p++) {
            const int n = lp_r + 32 * p;
            const ushort4 wv = *(const ushort4*)(WblkT + (size_t)n * HID_ + kt * 32 + lp_c * 4);
            *(ushort4*)(&b_s[n * 40 + lp_c * 4]) = wv;
        }
        __syncthreads();
        short8 af[4], bfr[4];
#pragma unroll
        for (int mi = 0; mi < 4; mi++)
            af[mi] = *(const short8*)(&hb_s[(wrow * 64 + mi * 16 + lm) * 136 + kt * 32 + quad * 8]);
#pragma unroll
        for (int ni = 0; ni < 4; ni++)
            bfr[ni] = *(const short8*)(&b_s[(wcol * 64 + ni * 16 + lm) * 40 + quad * 8]);
#pragma unroll
        for (int mi = 0; mi < 4; mi++)
#pragma unroll
            for (int ni = 0; ni < 4; ni++)
                acc[mi][ni] = __builtin_amdgcn_mfma_f32_16x16x32_bf16(af[mi], bfr[ni], acc[mi][ni], 0, 0, 0);
        __syncthreads();
    }

    // ---- epilogue 2: BN partial sums only (z not stored) ----
    {
        float bcol[4];
#pragma unroll
        for (int ni = 0; ni < 4; ni++) bcol[ni] = b_blk[wcol * 64 + ni * 16 + lm];
        float s_c[4] = {0.f, 0.f, 0.f, 0.f}, ss_c[4] = {0.f, 0.f, 0.f, 0.f};
#pragma unroll
        for (int mi = 0; mi < 4; mi++)
#pragma unroll
            for (int r = 0; r < 4; r++)
#pragma unroll
                for (int ni = 0; ni < 4; ni++) {
                    const float zv = acc[mi][ni][r] + bcol[ni];
                    s_c[ni] += zv;
                    ss_c[ni] += zv * zv;
                }
#pragma unroll
        for (int ni = 0; ni < 4; ni++) {
            atomicAdd(&csum_s[wcol * 64 + ni * 16 + lm], s_c[ni]);
            atomicAdd(&csumsq_s[wcol * 64 + ni * 16 + lm], ss_c[ni]);
        }
    }
    __syncthreads();
    if (tid < 128) {
        sumP[(size_t)blockIdx.x * 128 + tid] = csum_s[tid];
        sumsqP[(size_t)blockIdx.x * 128 + tid] = csumsq_s[tid];
    }
}

// ---------------- BN finalize ----------------------------------------------
__global__ __launch_bounds__(256) void k_bnfin(
    const float* __restrict__ sumP, const float* __restrict__ sumsqP,
    const float* __restrict__ gamma, const float* __restrict__ beta,
    float* __restrict__ scale, float* __restrict__ shift)
{
    const int c = blockIdx.x;
    const int tid = threadIdx.x;
    float s = 0.f, ss = 0.f;
    for (int i = tid; i < 1024; i += 256) {
        s  += sumP[(size_t)i * 128 + c];
        ss += sumsqP[(size_t)i * 128 + c];
    }
#pragma unroll
    for (int off = 32; off; off >>= 1) {
        s  += __shfl_xor(s, off, 64);
        ss += __shfl_xor(ss, off, 64);
    }
    __shared__ float rs[4], rss[4];
    const int wid = tid >> 6, lane = tid & 63;
    if (lane == 0) { rs[wid] = s; rss[wid] = ss; }
    __syncthreads();
    if (tid == 0) {
        const float S  = rs[0] + rs[1] + rs[2] + rs[3];
        const float SS = rss[0] + rss[1] + rss[2] + rss[3];
        const float inv_m = 1.0f / (float)MB_;
        const float mu = S * inv_m;
        const float var = SS * inv_m - mu * mu;
        const float sc = gamma[c] * rsqrtf(var + 1e-5f);
        scale[c] = sc;
        shift[c] = beta[c] - mu * sc;
    }
}

// ---------------- Phase C: recompute z, BN apply, residual, logits, t -------
// grid 1024 (128 rows each), block 256. Writes t in (b,h,o) layout.
__global__ __launch_bounds__(256) void k_phaseC(
    const unsigned short* __restrict__ h_in, const unsigned short* __restrict__ WblkT,
    const float* __restrict__ b_blk,
    const float* __restrict__ scale, const float* __restrict__ shift,
    const float* __restrict__ W_fc, const float* __restrict__ b_fc,
    const float* __restrict__ mask, const float* __restrict__ gumbel,
    float* __restrict__ t_bho)
{
    __shared__ unsigned short hb_s[128 * 136];
    __shared__ unsigned short b_s[128 * 40];
    __shared__ float wfc_s[128 * 8];
    __shared__ float sc_s[128], sh_s[128];

    const int tid = threadIdx.x;
    const int R0 = blockIdx.x * 128;
    const int wave = tid >> 6;
    const int wrow = wave >> 1, wcol = wave & 1;
    const int lane = tid & 63;
    const int lm = lane & 15, quad = lane >> 4;
    const int lp_r = tid >> 3, lp_c = tid & 7;

    for (int i = tid; i < 1024; i += 256) wfc_s[i] = W_fc[i];
    if (tid < 128) { sc_s[tid] = scale[tid]; sh_s[tid] = shift[tid]; }
    // stage h tile (coalesced)
    {
        const int row = tid >> 1, half = tid & 1;
#pragma unroll
        for (int c8 = 0; c8 < 8; c8++) {
            const short8 v = *(const short8*)(h_in + (size_t)(R0 + row) * HID_ + half * 64 + c8 * 8);
            *(short8*)(&hb_s[row * 136 + half * 64 + c8 * 8]) = v;
        }
    }
    __syncthreads();

    f32x4 acc[4][4];
#pragma unroll
    for (int i = 0; i < 4; i++)
#pragma unroll
        for (int j = 0; j < 4; j++) acc[i][j] = (f32x4){0.f, 0.f, 0.f, 0.f};
    for (int kt = 0; kt < 4; kt++) {
#pragma unroll
        for (int p = 0; p < 4; p++) {
            const int n = lp_r + 32 * p;
            const ushort4 wv = *(const ushort4*)(WblkT + (size_t)n * HID_ + kt * 32 + lp_c * 4);
            *(ushort4*)(&b_s[n * 40 + lp_c * 4]) = wv;
        }
        __syncthreads();
        short8 af[4], bfr[4];
#pragma unroll
        for (int mi = 0; mi < 4; mi++)
            af[mi] = *(const short8*)(&hb_s[(wrow * 64 + mi * 16 + lm) * 136 + kt * 32 + quad * 8]);
#pragma unroll
        for (int ni = 0; ni < 4; ni++)
            bfr[ni] = *(const short8*)(&b_s[(wcol * 64 + ni * 16 + lm) * 40 + quad * 8]);
#pragma unroll
        for (int mi = 0; mi < 4; mi++)
#pragma unroll
            for (int ni = 0; ni < 4; ni++)
                acc[mi][ni] = __builtin_amdgcn_mfma_f32_16x16x32_bf16(af[mi], bfr[ni], acc[mi][ni], 0, 0, 0);
        __syncthreads();
    }

    // epilogue: hb = relu(z*sc+sh) + h, in place (each element owned by one thread)
    {
        float bcol[4];
#pragma unroll
        for (int ni = 0; ni < 4; ni++) bcol[ni] = b_blk[wcol * 64 + ni * 16 + lm];
#pragma unroll
        for (int mi = 0; mi < 4; mi++)
#pragma unroll
            for (int r = 0; r < 4; r++) {
                const int row = wrow * 64 + mi * 16 + quad * 4 + r;
#pragma unroll
                for (int ni = 0; ni < 4; ni++) {
                    const int col = wcol * 64 + ni * 16 + lm;
                    const float zv = acc[mi][ni][r] + bcol[ni];
                    const float hv = bf2f(hb_s[row * 136 + col]);
                    const float hb = fmaxf(zv * sc_s[col] + sh_s[col], 0.f) + hv;
                    hb_s[row * 136 + col] = f2bf(hb);
                }
            }
    }
    __syncthreads();

    // logits + gumbel, t in (b,h,o) layout
    if (tid < 128) {
        const int row = tid;
        const int grow = R0 + row;
        const int b = grow >> 12, o = grow & 4095;
        float a8[8];
#pragma unroll
        for (int j = 0; j < 8; j++) a8[j] = 0.f;
#pragma unroll 4
        for (int k8 = 0; k8 < 16; k8++) {
            const short8 hv8 = *(const short8*)(&hb_s[row * 136 + k8 * 8]);
#pragma unroll
            for (int e = 0; e < 8; e++) {
                const float hv = bf2f((unsigned short)hv8[e]);
                const int k = k8 * 8 + e;
#pragma unroll
                for (int j = 0; j < 8; j++) a8[j] += hv * wfc_s[k * 8 + j];
            }
        }
        const float mk = mask[grow];
        const float* gp = gumbel + (size_t)grow * 8;
#pragma unroll
        for (int j = 0; j < 8; j++) {
            const float t = (a8[j] + b_fc[j]) * mk + gp[j];
            t_bho[((size_t)(b * 8 + j)) * O_ + o] = t;
        }
    }
}

// ---------------- softmax over O per (b,h), coalesced -----------------------
__global__ __launch_bounds__(256) void k_softmax(
    const float* __restrict__ t_in, float* __restrict__ w_out)
{
    const int bh = blockIdx.x;
    const int tid = threadIdx.x;
    const float* tp = t_in + (size_t)bh * O_;
    float4 v[4];
    float mx = -3.4e38f;
#pragma unroll
    for (int it = 0; it < 4; it++) {
        v[it] = *(const float4*)(tp + it * 1024 + tid * 4);
        mx = fmaxf(mx, fmaxf(fmaxf(v[it].x, v[it].y), fmaxf(v[it].z, v[it].w)));
    }
#pragma unroll
    for (int off = 32; off; off >>= 1) mx = fmaxf(mx, __shfl_xor(mx, off, 64));
    __shared__ float rm[4], rsum[4];
    const int wid = tid >> 6, lane = tid & 63;
    if (lane == 0) rm[wid] = mx;
    __syncthreads();
    mx = fmaxf(fmaxf(rm[0], rm[1]), fmaxf(rm[2], rm[3]));
    float sum = 0.f;
#pragma unroll
    for (int it = 0; it < 4; it++) {
        v[it].x = __expf(v[it].x - mx); v[it].y = __expf(v[it].y - mx);
        v[it].z = __expf(v[it].z - mx); v[it].w = __expf(v[it].w - mx);
        sum += v[it].x + v[it].y + v[it].z + v[it].w;
    }
#pragma unroll
    for (int off = 32; off; off >>= 1) sum += __shfl_xor(sum, off, 64);
    if (lane == 0) rsum[wid] = sum;
    __syncthreads();
    sum = rsum[0] + rsum[1] + rsum[2] + rsum[3];
    const float inv = 1.f / sum;
    float* wp = w_out + (size_t)bh * O_;
#pragma unroll
    for (int it = 0; it < 4; it++) {
        float4 o;
        o.x = v[it].x * inv; o.y = v[it].y * inv; o.z = v[it].z * inv; o.w = v[it].w * inv;
        *(float4*)(wp + it * 1024 + tid * 4) = o;
    }
}

// ---------------- pooled partials -------------------------------------------
// grid (oc=32, b=32). Wave w owns f-range [w*64, w*64+64); 128 o-rows/block.
__global__ __launch_bounds__(256) void k_pool(
    const float* __restrict__ x, const float* __restrict__ w_in,
    float* __restrict__ pp)
{
    __shared__ float ws_s[8][128];
    const int tid = threadIdx.x;
    const int oc = blockIdx.x;
    const int b = blockIdx.y;
    const int wave = tid >> 6, lane = tid & 63;
    const int f = wave * 64 + lane;
    for (int i = tid; i < 1024; i += 256) {
        const int hh = i >> 7, oi = i & 127;
        ws_s[hh][oi] = w_in[((size_t)(b * 8 + hh)) * O_ + oc * 128 + oi];
    }
    __syncthreads();
    float acc[8];
#pragma unroll
    for (int hh = 0; hh < 8; hh++) acc[hh] = 0.f;
    const float* xp = x + ((size_t)(b * O_ + oc * 128)) * F_ + f;
#pragma unroll 1
    for (int oi = 0; oi < 128; oi += 4) {
        float xv[4];
#pragma unroll
        for (int u = 0; u < 4; u++) xv[u] = xp[(size_t)(oi + u) * F_];
#pragma unroll
        for (int u = 0; u < 4; u++)
#pragma unroll
            for (int hh = 0; hh < 8; hh++) acc[hh] += ws_s[hh][oi + u] * xv[u];
    }
    float* outp = pp + ((size_t)(oc * 32 + b)) * 2048;
#pragma unroll
    for (int hh = 0; hh < 8; hh++) outp[hh * 256 + f] = acc[hh];
}

// ---------------- reduce pooled partials ------------------------------------
__global__ __launch_bounds__(256) void k_reduce_pool(
    const float* __restrict__ pp, float* __restrict__ out)
{
    const size_t i = (size_t)blockIdx.x * 256 + threadIdx.x;
    float s = 0.f;
#pragma unroll
    for (int oc = 0; oc < 32; oc++) s += pp[(size_t)oc * 65536 + i];
    out[i] = s;
}

extern "C" void kernel_launch(void* const* d_in, const int* in_sizes, int n_in,
                              void* d_out, int out_size, void* d_ws, size_t ws_size,
                              hipStream_t stream)
{
    const float* x      = (const float*)d_in[0];
    const float* gumbel = (const float*)d_in[1];
    const float* W_in   = (const float*)d_in[2];
    const float* b_in   = (const float*)d_in[3];
    const float* W_blk  = (const float*)d_in[4];
    const float* b_blk  = (const float*)d_in[5];
    const float* gamma  = (const float*)d_in[6];
    const float* beta   = (const float*)d_in[7];
    const float* W_fc   = (const float*)d_in[8];
    const float* b_fc   = (const float*)d_in[9];
    float* out = (float*)d_out;
    char* ws = (char*)d_ws;

    unsigned short* h_bf  = (unsigned short*)(ws + 0);             // 33554432
    float* mask   = (float*)(ws + 33554432);                        // 524288
    float* sumP   = (float*)(ws + 34078720);                        // 524288
    float* sumsqP = (float*)(ws + 34603008);                        // 524288
    float* scale  = (float*)(ws + 35127296);                        // 512
    float* shift  = (float*)(ws + 35127808);                        // 512
    float* t_buf  = (float*)(ws + 35128320);                        // 4194304
    float* w_buf  = (float*)(ws + 39322624);                        // 4194304
    float* pp     = (float*)(ws + 43516928);                        // 8388608
    unsigned short* WinT  = (unsigned short*)(ws + 51905536);       // 65536
    unsigned short* WblkT = (unsigned short*)(ws + 51971072);       // 32768

    k_prep<<<192, 256, 0, stream>>>(W_in, W_blk, WinT, WblkT);
    k_phaseA<<<1024, 256, 0, stream>>>(x, WinT, WblkT, b_in, b_blk, h_bf, mask, sumP, sumsqP);
    k_bnfin<<<128, 256, 0, stream>>>(sumP, sumsqP, gamma, beta, scale, shift);
    k_phaseC<<<1024, 256, 0, stream>>>(h_bf, WblkT, b_blk, scale, shift, W_fc, b_fc, mask, gumbel, t_buf);
    k_softmax<<<256, 256, 0, stream>>>(t_buf, w_buf);
    k_pool<<<dim3(32, 32), 256, 0, stream>>>(x, w_buf, pp);
    k_reduce_pool<<<256, 256, 0, stream>>>(pp, out);
}

// Round 4
// 312.977 us; speedup vs baseline: 1.0174x; 1.0174x over previous
//
#include <hip/hip_runtime.h>
#include <hip/hip_bf16.h>
#include <math.h>

// Problem constants: B=32, O=4096, F=256, H=8, HID=128
#define MB_ 131072
#define F_  256
#define HID_ 128
#define H_  8
#define O_  4096
#define B_  32

typedef __attribute__((ext_vector_type(8))) short short8;
typedef __attribute__((ext_vector_type(4))) float f32x4;

static __device__ __forceinline__ unsigned short f2bf(float f) {
    unsigned int u = __float_as_uint(f);
    unsigned int r = (u + 0x7fffu + ((u >> 16) & 1u)) >> 16;  // RNE
    return (unsigned short)r;
}
static __device__ __forceinline__ float bf2f(unsigned short u) {
    return __uint_as_float(((unsigned int)u) << 16);
}
// packed 2xf32 -> 2xbf16 (v_cvt_pk_bf16_f32 on gfx950)
static __device__ __forceinline__ unsigned int pk2bf(float a, float b) {
    float2 f2; f2.x = a; f2.y = b;
    __hip_bfloat162 h = __float22bfloat162_rn(f2);
    union { __hip_bfloat162 h2; unsigned int u; } cv;
    cv.h2 = h;
    return cv.u;
}

// ---------------- Prep: transpose + bf16-cast weights -----------------------
__global__ __launch_bounds__(256) void k_prep(
    const float* __restrict__ W_in, const float* __restrict__ W_blk,
    unsigned short* __restrict__ WinT, unsigned short* __restrict__ WblkT)
{
    const int idx = blockIdx.x * 256 + threadIdx.x;
    if (idx < 32768) {
        const int n = idx >> 8, k = idx & 255;
        WinT[idx] = f2bf(W_in[(size_t)k * HID_ + n]);
    } else {
        const int i2 = idx - 32768;  // < 16384
        const int n = i2 >> 7, k = i2 & 127;
        WblkT[i2] = f2bf(W_blk[(size_t)k * HID_ + n]);
    }
}

// ---------------- Phase A: h = relu(x@W_in+b_in); BN partials of z ----------
// grid 1024, block 256 (4 waves), 128 rows/block.
// A/B fragments loaded DIRECTLY from global (no LDS staging, no K-loop syncs).
// Only the h tile lives in LDS (cross-wave exchange for GEMM2 + coalesced store).
__global__ __launch_bounds__(256, 4) void k_phaseA(
    const float* __restrict__ x, const unsigned short* __restrict__ WinT,
    const unsigned short* __restrict__ WblkT,
    const float* __restrict__ b_in, const float* __restrict__ b_blk,
    unsigned short* __restrict__ h_out, float* __restrict__ mask_out,
    float* __restrict__ sumP, float* __restrict__ sumsqP)
{
    __shared__ unsigned short hb_s[128 * 136];   // h tile, LDH=136 (16B rows)
    __shared__ float csum_s[128], csumsq_s[128];

    const int tid = threadIdx.x;
    const int R0 = blockIdx.x * 128;
    const int wave = tid >> 6;
    const int wrow = wave >> 1, wcol = wave & 1;
    const int lane = tid & 63;
    const int lm = lane & 15, quad = lane >> 4;

    if (tid < 128) { csum_s[tid] = 0.f; csumsq_s[tid] = 0.f; }

    f32x4 acc[4][4];
#pragma unroll
    for (int i = 0; i < 4; i++)
#pragma unroll
        for (int j = 0; j < 4; j++) acc[i][j] = (f32x4){0.f, 0.f, 0.f, 0.f};
    float ms[4] = {0.f, 0.f, 0.f, 0.f};

    const float* xb = x + (size_t)(R0 + wrow * 64 + lm) * F_;
    const unsigned short* wb = WinT + (size_t)(wcol * 64 + lm) * F_;

    // ---- GEMM1: K = 256 in 8 steps of 32, fully barrier-free ----
#pragma unroll 2
    for (int kt = 0; kt < 8; kt++) {
        const int kof = kt * 32 + quad * 8;
        short8 af[4], bfr[4];
#pragma unroll
        for (int mi = 0; mi < 4; mi++) {
            const float4 v0 = *(const float4*)(xb + (size_t)mi * 16 * F_ + kof);
            const float4 v1 = *(const float4*)(xb + (size_t)mi * 16 * F_ + kof + 4);
            ms[mi] += v0.x * v0.x + v0.y * v0.y + v0.z * v0.z + v0.w * v0.w
                    + v1.x * v1.x + v1.y * v1.y + v1.z * v1.z + v1.w * v1.w;
            union { short8 s8; unsigned int u[4]; } fr;
            fr.u[0] = pk2bf(v0.x, v0.y);
            fr.u[1] = pk2bf(v0.z, v0.w);
            fr.u[2] = pk2bf(v1.x, v1.y);
            fr.u[3] = pk2bf(v1.z, v1.w);
            af[mi] = fr.s8;
        }
#pragma unroll
        for (int ni = 0; ni < 4; ni++)
            bfr[ni] = *(const short8*)(wb + (size_t)ni * 16 * F_ + kof);
#pragma unroll
        for (int mi = 0; mi < 4; mi++)
#pragma unroll
            for (int ni = 0; ni < 4; ni++)
                acc[mi][ni] = __builtin_amdgcn_mfma_f32_16x16x32_bf16(af[mi], bfr[ni], acc[mi][ni], 0, 0, 0);
    }

    // ---- row mask: reduce x^2 over quads; wcol==0 waves own the write ----
#pragma unroll
    for (int mi = 0; mi < 4; mi++) {
        float s = ms[mi];
        s += __shfl_xor(s, 16);
        s += __shfl_xor(s, 32);
        if (wcol == 0 && quad == 0)
            mask_out[R0 + wrow * 64 + mi * 16 + lm] = (s != 0.f) ? 1.f : 0.f;
    }

    // ---- epilogue 1: bias + relu -> hb_s ----
    {
        float bcol[4];
#pragma unroll
        for (int ni = 0; ni < 4; ni++) bcol[ni] = b_in[wcol * 64 + ni * 16 + lm];
#pragma unroll
        for (int mi = 0; mi < 4; mi++)
#pragma unroll
            for (int r = 0; r < 4; r++) {
                const int row = wrow * 64 + mi * 16 + quad * 4 + r;
#pragma unroll
                for (int ni = 0; ni < 4; ni++) {
                    const int col = wcol * 64 + ni * 16 + lm;
                    hb_s[row * 136 + col] = f2bf(fmaxf(acc[mi][ni][r] + bcol[ni], 0.f));
                }
            }
    }
    __syncthreads();

    // ---- coalesced h store from LDS ----
    {
        const int row = tid >> 1, half = tid & 1;
#pragma unroll
        for (int c8 = 0; c8 < 8; c8++) {
            const short8 v = *(const short8*)(&hb_s[row * 136 + half * 64 + c8 * 8]);
            *(short8*)(h_out + (size_t)(R0 + row) * HID_ + half * 64 + c8 * 8) = v;
        }
    }

    // ---- GEMM2: z = h @ W_blk (A from hb_s, B direct global), no syncs ----
#pragma unroll
    for (int i = 0; i < 4; i++)
#pragma unroll
        for (int j = 0; j < 4; j++) acc[i][j] = (f32x4){0.f, 0.f, 0.f, 0.f};
    const unsigned short* wb2 = WblkT + (size_t)(wcol * 64 + lm) * HID_;
#pragma unroll
    for (int kt = 0; kt < 4; kt++) {
        const int kof = kt * 32 + quad * 8;
        short8 af[4], bfr[4];
#pragma unroll
        for (int mi = 0; mi < 4; mi++)
            af[mi] = *(const short8*)(&hb_s[(wrow * 64 + mi * 16 + lm) * 136 + kof]);
#pragma unroll
        for (int ni = 0; ni < 4; ni++)
            bfr[ni] = *(const short8*)(wb2 + (size_t)ni * 16 * HID_ + kof);
#pragma unroll
        for (int mi = 0; mi < 4; mi++)
#pragma unroll
            for (int ni = 0; ni < 4; ni++)
                acc[mi][ni] = __builtin_amdgcn_mfma_f32_16x16x32_bf16(af[mi], bfr[ni], acc[mi][ni], 0, 0, 0);
    }

    // ---- epilogue 2: BN partial sums (z never stored) ----
    {
        float bcol[4];
#pragma unroll
        for (int ni = 0; ni < 4; ni++) bcol[ni] = b_blk[wcol * 64 + ni * 16 + lm];
        float s_c[4] = {0.f, 0.f, 0.f, 0.f}, ss_c[4] = {0.f, 0.f, 0.f, 0.f};
#pragma unroll
        for (int mi = 0; mi < 4; mi++)
#pragma unroll
            for (int r = 0; r < 4; r++)
#pragma unroll
                for (int ni = 0; ni < 4; ni++) {
                    const float zv = acc[mi][ni][r] + bcol[ni];
                    s_c[ni] += zv;
                    ss_c[ni] += zv * zv;
                }
#pragma unroll
        for (int ni = 0; ni < 4; ni++) {
            float s = s_c[ni], ss = ss_c[ni];
            s  += __shfl_xor(s, 16);  s  += __shfl_xor(s, 32);
            ss += __shfl_xor(ss, 16); ss += __shfl_xor(ss, 32);
            if (quad == 0) {
                atomicAdd(&csum_s[wcol * 64 + ni * 16 + lm], s);
                atomicAdd(&csumsq_s[wcol * 64 + ni * 16 + lm], ss);
            }
        }
    }
    __syncthreads();
    if (tid < 128) {
        sumP[(size_t)blockIdx.x * 128 + tid] = csum_s[tid];
        sumsqP[(size_t)blockIdx.x * 128 + tid] = csumsq_s[tid];
    }
}

// ---------------- BN finalize ----------------------------------------------
__global__ __launch_bounds__(256) void k_bnfin(
    const float* __restrict__ sumP, const float* __restrict__ sumsqP,
    const float* __restrict__ gamma, const float* __restrict__ beta,
    float* __restrict__ scale, float* __restrict__ shift)
{
    const int c = blockIdx.x;
    const int tid = threadIdx.x;
    float s = 0.f, ss = 0.f;
    for (int i = tid; i < 1024; i += 256) {
        s  += sumP[(size_t)i * 128 + c];
        ss += sumsqP[(size_t)i * 128 + c];
    }
#pragma unroll
    for (int off = 32; off; off >>= 1) {
        s  += __shfl_xor(s, off, 64);
        ss += __shfl_xor(ss, off, 64);
    }
    __shared__ float rs[4], rss[4];
    const int wid = tid >> 6, lane = tid & 63;
    if (lane == 0) { rs[wid] = s; rss[wid] = ss; }
    __syncthreads();
    if (tid == 0) {
        const float S  = rs[0] + rs[1] + rs[2] + rs[3];
        const float SS = rss[0] + rss[1] + rss[2] + rss[3];
        const float inv_m = 1.0f / (float)MB_;
        const float mu = S * inv_m;
        const float var = SS * inv_m - mu * mu;
        const float sc = gamma[c] * rsqrtf(var + 1e-5f);
        scale[c] = sc;
        shift[c] = beta[c] - mu * sc;
    }
}

// ---------------- Phase C: recompute z, BN, residual, logits, t -------------
// grid 1024 (128 rows), block 256. B-frags direct from global. t in (b,h,o).
__global__ __launch_bounds__(256, 4) void k_phaseC(
    const unsigned short* __restrict__ h_in, const unsigned short* __restrict__ WblkT,
    const float* __restrict__ b_blk,
    const float* __restrict__ scale, const float* __restrict__ shift,
    const float* __restrict__ W_fc, const float* __restrict__ b_fc,
    const float* __restrict__ mask, const float* __restrict__ gumbel,
    float* __restrict__ t_bho)
{
    __shared__ unsigned short hb_s[128 * 136];
    __shared__ float wfc_s[128 * 8];
    __shared__ float sc_s[128], sh_s[128];

    const int tid = threadIdx.x;
    const int R0 = blockIdx.x * 128;
    const int wave = tid >> 6;
    const int wrow = wave >> 1, wcol = wave & 1;
    const int lane = tid & 63;
    const int lm = lane & 15, quad = lane >> 4;

    for (int i = tid; i < 1024; i += 256) wfc_s[i] = W_fc[i];
    if (tid < 128) { sc_s[tid] = scale[tid]; sh_s[tid] = shift[tid]; }
    // stage h tile (coalesced)
    {
        const int row = tid >> 1, half = tid & 1;
#pragma unroll
        for (int c8 = 0; c8 < 8; c8++) {
            const short8 v = *(const short8*)(h_in + (size_t)(R0 + row) * HID_ + half * 64 + c8 * 8);
            *(short8*)(&hb_s[row * 136 + half * 64 + c8 * 8]) = v;
        }
    }
    __syncthreads();

    f32x4 acc[4][4];
#pragma unroll
    for (int i = 0; i < 4; i++)
#pragma unroll
        for (int j = 0; j < 4; j++) acc[i][j] = (f32x4){0.f, 0.f, 0.f, 0.f};
    const unsigned short* wb2 = WblkT + (size_t)(wcol * 64 + lm) * HID_;
#pragma unroll
    for (int kt = 0; kt < 4; kt++) {
        const int kof = kt * 32 + quad * 8;
        short8 af[4], bfr[4];
#pragma unroll
        for (int mi = 0; mi < 4; mi++)
            af[mi] = *(const short8*)(&hb_s[(wrow * 64 + mi * 16 + lm) * 136 + kof]);
#pragma unroll
        for (int ni = 0; ni < 4; ni++)
            bfr[ni] = *(const short8*)(wb2 + (size_t)ni * 16 * HID_ + kof);
#pragma unroll
        for (int mi = 0; mi < 4; mi++)
#pragma unroll
            for (int ni = 0; ni < 4; ni++)
                acc[mi][ni] = __builtin_amdgcn_mfma_f32_16x16x32_bf16(af[mi], bfr[ni], acc[mi][ni], 0, 0, 0);
    }

    // epilogue: hb = relu(z*sc+sh) + h, in place
    {
        float bcol[4];
#pragma unroll
        for (int ni = 0; ni < 4; ni++) bcol[ni] = b_blk[wcol * 64 + ni * 16 + lm];
#pragma unroll
        for (int mi = 0; mi < 4; mi++)
#pragma unroll
            for (int r = 0; r < 4; r++) {
                const int row = wrow * 64 + mi * 16 + quad * 4 + r;
#pragma unroll
                for (int ni = 0; ni < 4; ni++) {
                    const int col = wcol * 64 + ni * 16 + lm;
                    const float zv = acc[mi][ni][r] + bcol[ni];
                    const float hv = bf2f(hb_s[row * 136 + col]);
                    const float hb = fmaxf(zv * sc_s[col] + sh_s[col], 0.f) + hv;
                    hb_s[row * 136 + col] = f2bf(hb);
                }
            }
    }
    __syncthreads();

    // logits + gumbel, t in (b,h,o) layout
    if (tid < 128) {
        const int row = tid;
        const int grow = R0 + row;
        const int b = grow >> 12, o = grow & 4095;
        float a8[8];
#pragma unroll
        for (int j = 0; j < 8; j++) a8[j] = 0.f;
#pragma unroll 4
        for (int k8 = 0; k8 < 16; k8++) {
            const short8 hv8 = *(const short8*)(&hb_s[row * 136 + k8 * 8]);
#pragma unroll
            for (int e = 0; e < 8; e++) {
                const float hv = bf2f((unsigned short)hv8[e]);
                const int k = k8 * 8 + e;
#pragma unroll
                for (int j = 0; j < 8; j++) a8[j] += hv * wfc_s[k * 8 + j];
            }
        }
        const float mk = mask[grow];
        const float* gp = gumbel + (size_t)grow * 8;
#pragma unroll
        for (int j = 0; j < 8; j++) {
            const float t = (a8[j] + b_fc[j]) * mk + gp[j];
            t_bho[((size_t)(b * 8 + j)) * O_ + o] = t;
        }
    }
}

// ---------------- softmax over O per (b,h), coalesced -----------------------
__global__ __launch_bounds__(256) void k_softmax(
    const float* __restrict__ t_in, float* __restrict__ w_out)
{
    const int bh = blockIdx.x;
    const int tid = threadIdx.x;
    const float* tp = t_in + (size_t)bh * O_;
    float4 v[4];
    float mx = -3.4e38f;
#pragma unroll
    for (int it = 0; it < 4; it++) {
        v[it] = *(const float4*)(tp + it * 1024 + tid * 4);
        mx = fmaxf(mx, fmaxf(fmaxf(v[it].x, v[it].y), fmaxf(v[it].z, v[it].w)));
    }
#pragma unroll
    for (int off = 32; off; off >>= 1) mx = fmaxf(mx, __shfl_xor(mx, off, 64));
    __shared__ float rm[4], rsum[4];
    const int wid = tid >> 6, lane = tid & 63;
    if (lane == 0) rm[wid] = mx;
    __syncthreads();
    mx = fmaxf(fmaxf(rm[0], rm[1]), fmaxf(rm[2], rm[3]));
    float sum = 0.f;
#pragma unroll
    for (int it = 0; it < 4; it++) {
        v[it].x = __expf(v[it].x - mx); v[it].y = __expf(v[it].y - mx);
        v[it].z = __expf(v[it].z - mx); v[it].w = __expf(v[it].w - mx);
        sum += v[it].x + v[it].y + v[it].z + v[it].w;
    }
#pragma unroll
    for (int off = 32; off; off >>= 1) sum += __shfl_xor(sum, off, 64);
    if (lane == 0) rsum[wid] = sum;
    __syncthreads();
    sum = rsum[0] + rsum[1] + rsum[2] + rsum[3];
    const float inv = 1.f / sum;
    float* wp = w_out + (size_t)bh * O_;
#pragma unroll
    for (int it = 0; it < 4; it++) {
        float4 o;
        o.x = v[it].x * inv; o.y = v[it].y * inv; o.z = v[it].z * inv; o.w = v[it].w * inv;
        *(float4*)(wp + it * 1024 + tid * 4) = o;
    }
}

// ---------------- pooled partials -------------------------------------------
__global__ __launch_bounds__(256) void k_pool(
    const float* __restrict__ x, const float* __restrict__ w_in,
    float* __restrict__ pp)
{
    __shared__ float ws_s[8][128];
    const int tid = threadIdx.x;
    const int oc = blockIdx.x;
    const int b = blockIdx.y;
    const int wave = tid >> 6, lane = tid & 63;
    const int f = wave * 64 + lane;
    for (int i = tid; i < 1024; i += 256) {
        const int hh = i >> 7, oi = i & 127;
        ws_s[hh][oi] = w_in[((size_t)(b * 8 + hh)) * O_ + oc * 128 + oi];
    }
    __syncthreads();
    float acc[8];
#pragma unroll
    for (int hh = 0; hh < 8; hh++) acc[hh] = 0.f;
    const float* xp = x + ((size_t)(b * O_ + oc * 128)) * F_ + f;
#pragma unroll 1
    for (int oi = 0; oi < 128; oi += 4) {
        float xv[4];
#pragma unroll
        for (int u = 0; u < 4; u++) xv[u] = xp[(size_t)(oi + u) * F_];
#pragma unroll
        for (int u = 0; u < 4; u++)
#pragma unroll
            for (int hh = 0; hh < 8; hh++) acc[hh] += ws_s[hh][oi + u] * xv[u];
    }
    float* outp = pp + ((size_t)(oc * 32 + b)) * 2048;
#pragma unroll
    for (int hh = 0; hh < 8; hh++) outp[hh * 256 + f] = acc[hh];
}

// ---------------- reduce pooled partials ------------------------------------
__global__ __launch_bounds__(256) void k_reduce_pool(
    const float* __restrict__ pp, float* __restrict__ out)
{
    const size_t i = (size_t)blockIdx.x * 256 + threadIdx.x;
    float s = 0.f;
#pragma unroll
    for (int oc = 0; oc < 32; oc++) s += pp[(size_t)oc * 65536 + i];
    out[i] = s;
}

extern "C" void kernel_launch(void* const* d_in, const int* in_sizes, int n_in,
                              void* d_out, int out_size, void* d_ws, size_t ws_size,
                              hipStream_t stream)
{
    const float* x      = (const float*)d_in[0];
    const float* gumbel = (const float*)d_in[1];
    const float* W_in   = (const float*)d_in[2];
    const float* b_in   = (const float*)d_in[3];
    const float* W_blk  = (const float*)d_in[4];
    const float* b_blk  = (const float*)d_in[5];
    const float* gamma  = (const float*)d_in[6];
    const float* beta   = (const float*)d_in[7];
    const float* W_fc   = (const float*)d_in[8];
    const float* b_fc   = (const float*)d_in[9];
    float* out = (float*)d_out;
    char* ws = (char*)d_ws;

    unsigned short* h_bf  = (unsigned short*)(ws + 0);             // 33554432
    float* mask   = (float*)(ws + 33554432);                        // 524288
    float* sumP   = (float*)(ws + 34078720);                        // 524288
    float* sumsqP = (float*)(ws + 34603008);                        // 524288
    float* scale  = (float*)(ws + 35127296);                        // 512
    float* shift  = (float*)(ws + 35127808);                        // 512
    float* t_buf  = (float*)(ws + 35128320);                        // 4194304
    float* w_buf  = (float*)(ws + 39322624);                        // 4194304
    float* pp     = (float*)(ws + 43516928);                        // 8388608
    unsigned short* WinT  = (unsigned short*)(ws + 51905536);       // 65536
    unsigned short* WblkT = (unsigned short*)(ws + 51971072);       // 32768

    k_prep<<<192, 256, 0, stream>>>(W_in, W_blk, WinT, WblkT);
    k_phaseA<<<1024, 256, 0, stream>>>(x, WinT, WblkT, b_in, b_blk, h_bf, mask, sumP, sumsqP);
    k_bnfin<<<128, 256, 0, stream>>>(sumP, sumsqP, gamma, beta, scale, shift);
    k_phaseC<<<1024, 256, 0, stream>>>(h_bf, WblkT, b_blk, scale, shift, W_fc, b_fc, mask, gumbel, t_buf);
    k_softmax<<<256, 256, 0, stream>>>(t_buf, w_buf);
    k_pool<<<dim3(32, 32), 256, 0, stream>>>(x, w_buf, pp);
    k_reduce_pool<<<256, 256, 0, stream>>>(pp, out);
}